// Round 13
// baseline (308.992 us; speedup 1.0000x reference)
//
#include <hip/hip_runtime.h>
#include <cstdint>

#define NROWS 131072
#define HD    128      // H == IN == 128
#define NDIM  512      // 4*H
#define OUTQ  16777216 // NROWS*HD

using bf16x8 = __attribute__((ext_vector_type(8))) short;
using f32x4  = __attribute__((ext_vector_type(4))) float;

__device__ __forceinline__ uint32_t bf16rne(float f) {
  uint32_t u = __builtin_bit_cast(uint32_t, f);
  return (u + 0x7fffu + ((u >> 16) & 1u)) >> 16;
}

__device__ __forceinline__ float tanhf_fast(float v) {
  float a = __builtin_fabsf(v);
  float e = __expf(-2.0f * a);
  float t = (1.0f - e) * __builtin_amdgcn_rcpf(1.0f + e);
  return v < 0.0f ? -t : t;
}

__device__ __forceinline__ f32x4 ldv(const float* p) {
  return *reinterpret_cast<const f32x4*>(p);
}

// Pack Wf[k][n] = W[k][n] + (k>=128 ? r[k-128][n] : 0) as bf16 A-fragments
// of Wf^T with a PERMUTED row->gate-col map. Half-step u = t2*2+p of
// mega-tile t2 (32 gate cols): A-row m (0..15) maps to within-gate col
//   t2*32 + (m>>2)*8 + p*4 + (m&3)
// so a lane's D fragment (m = 4*lg + rr over p=0,1) covers the 8
// CONTIGUOUS cols t2*32 + lg*8 .. +7  -> full-line epilogue I/O.
// Frag (g*8 + u)*8 + s (1 KB): elem j of lane l = Wf[s*32+(l>>4)*8+j][ncol].
__global__ __launch_bounds__(256) void pack_weights(
    const float* __restrict__ W, const float* __restrict__ r,
    uint16_t* __restrict__ Bp) {
  int idx = blockIdx.x * 256 + threadIdx.x;   // 16384 frags total
  int l  = idx & 63;
  int ts = idx >> 6;
  int s  = ts & 7;
  int t  = ts >> 3;          // 0..31 = g*8 + u
  int g  = t >> 3;
  int u  = t & 7;
  int t2 = u >> 1;
  int p  = u & 1;
  int m  = l & 15;           // A-row index held by this lane
  int ncol  = g * 128 + t2 * 32 + ((m >> 2) << 3) + p * 4 + (m & 3);
  int kbase = s * 32 + ((l >> 4) << 3);
  uint32_t w[4];
#pragma unroll
  for (int jj = 0; jj < 4; ++jj) {
    int k0 = kbase + 2 * jj;
    float v0 = W[k0 * NDIM + ncol];
    float v1 = W[(k0 + 1) * NDIM + ncol];
    if (k0 >= 128)     v0 += r[(k0 - 128) * NDIM + ncol];
    if (k0 + 1 >= 128) v1 += r[(k0 + 1 - 128) * NDIM + ncol];
    w[jj] = bf16rne(v0) | (bf16rne(v1) << 16);
  }
  reinterpret_cast<uint4*>(Bp)[idx] = make_uint4(w[0], w[1], w[2], w[3]);
}

// 256 threads = 4 waves x 16 rows = 64 rows/block; 2048 blocks.
// No LDS, no barriers: weight fragments read directly from the packed
// L2/L3-resident buffer (16B/lane = 1KB/instruction, coalesced).
__global__ __launch_bounds__(256, 4) void slstm_fused(
    const float* __restrict__ x,  const float* __restrict__ h,
    const float* __restrict__ cs, const float* __restrict__ ns,
    const float* __restrict__ ms, const float* __restrict__ bias,
    const uint16_t* __restrict__ Bp, float* __restrict__ out) {
  const int tid  = threadIdx.x;
  const int wave = tid >> 6;
  const int lane = tid & 63;
  const int row0 = blockIdx.x * 64;
  const int l15  = lane & 15;
  const int lg   = lane >> 4;

  const int    myrow = row0 + wave * 16 + l15;
  const size_t rbase = (size_t)myrow * HD;
  const int    jb8   = lg * 8;   // lane's contiguous 8-col base in mega-tile

  // B-operand fragments direct from global: xh[myrow][s*32+lg*8+j], 32B contig.
  bf16x8 a[8];
#pragma unroll
  for (int s = 0; s < 8; ++s) {
    const float* src = (s < 4 ? x : h) + rbase + ((s & 3) * 32 + lg * 8);
    f32x4 v0 = ldv(src);
    f32x4 v1 = ldv(src + 4);
    bf16x8 pk;
    pk[0] = (short)bf16rne(v0[0]);
    pk[1] = (short)bf16rne(v0[1]);
    pk[2] = (short)bf16rne(v0[2]);
    pk[3] = (short)bf16rne(v0[3]);
    pk[4] = (short)bf16rne(v1[0]);
    pk[5] = (short)bf16rne(v1[1]);
    pk[6] = (short)bf16rne(v1[2]);
    pk[7] = (short)bf16rne(v1[3]);
    a[s] = pk;
  }

  const bf16x8* __restrict__ Bf = reinterpret_cast<const bf16x8*>(Bp);

  // ---- 4 mega-tiles x 2 half-steps, fully unrolled, self-paced ----
#pragma unroll
  for (int t2 = 0; t2 < 4; ++t2) {
    const int cb = t2 * 32 + jb8;        // lane's global col base (within H)

    // c/n/m loads for this mega-tile: 2 x f32x4 per array (full-line pairs).
    const f32x4 cvLo = ldv(cs + rbase + cb), cvHi = ldv(cs + rbase + cb + 4);
    const f32x4 nvLo = ldv(ns + rbase + cb), nvHi = ldv(ns + rbase + cb + 4);
    const f32x4 mvLo = ldv(ms + rbase + cb), mvHi = ldv(ms + rbase + cb + 4);

    const int u0 = 2 * t2, u1 = 2 * t2 + 1;
    f32x4 accI0 = {0,0,0,0}, accF0 = {0,0,0,0}, accZ0 = {0,0,0,0}, accO0 = {0,0,0,0};
#pragma unroll
    for (int s = 0; s < 8; ++s) {
      accI0 = __builtin_amdgcn_mfma_f32_16x16x32_bf16(Bf[(size_t)(((0 * 8 + u0) * 8) + s) * 64 + lane], a[s], accI0, 0, 0, 0);
      accF0 = __builtin_amdgcn_mfma_f32_16x16x32_bf16(Bf[(size_t)(((1 * 8 + u0) * 8) + s) * 64 + lane], a[s], accF0, 0, 0, 0);
      accZ0 = __builtin_amdgcn_mfma_f32_16x16x32_bf16(Bf[(size_t)(((2 * 8 + u0) * 8) + s) * 64 + lane], a[s], accZ0, 0, 0, 0);
      accO0 = __builtin_amdgcn_mfma_f32_16x16x32_bf16(Bf[(size_t)(((3 * 8 + u0) * 8) + s) * 64 + lane], a[s], accO0, 0, 0, 0);
    }
    f32x4 accI1 = {0,0,0,0}, accF1 = {0,0,0,0}, accZ1 = {0,0,0,0}, accO1 = {0,0,0,0};
#pragma unroll
    for (int s = 0; s < 8; ++s) {
      accI1 = __builtin_amdgcn_mfma_f32_16x16x32_bf16(Bf[(size_t)(((0 * 8 + u1) * 8) + s) * 64 + lane], a[s], accI1, 0, 0, 0);
      accF1 = __builtin_amdgcn_mfma_f32_16x16x32_bf16(Bf[(size_t)(((1 * 8 + u1) * 8) + s) * 64 + lane], a[s], accF1, 0, 0, 0);
      accZ1 = __builtin_amdgcn_mfma_f32_16x16x32_bf16(Bf[(size_t)(((2 * 8 + u1) * 8) + s) * 64 + lane], a[s], accZ1, 0, 0, 0);
      accO1 = __builtin_amdgcn_mfma_f32_16x16x32_bf16(Bf[(size_t)(((3 * 8 + u1) * 8) + s) * 64 + lane], a[s], accO1, 0, 0, 0);
    }

    // biases (L2-hot)
    const f32x4 bIlo = ldv(bias + cb),        bIhi = ldv(bias + cb + 4);
    const f32x4 bFlo = ldv(bias + 128 + cb),  bFhi = ldv(bias + 128 + cb + 4);
    const f32x4 bZlo = ldv(bias + 256 + cb),  bZhi = ldv(bias + 256 + cb + 4);
    const f32x4 bOlo = ldv(bias + 384 + cb),  bOhi = ldv(bias + 384 + cb + 4);

    // ---- epilogue: 8 contiguous cols/lane -> 2 full-line f32x4 IOs each ----
    f32x4 hnLo, hnHi, cnLo, cnHi, nnLo, nnHi, mnLo, mnHi;
#pragma unroll
    for (int d = 0; d < 8; ++d) {
      const int pp = d >> 2, rr = d & 3;
      const float i_raw = (pp ? accI1[rr] : accI0[rr]) + (pp ? bIhi[rr] : bIlo[rr]);
      const float f_raw = (pp ? accF1[rr] : accF0[rr]) + (pp ? bFhi[rr] : bFlo[rr]);
      const float z_raw = (pp ? accZ1[rr] : accZ0[rr]) + (pp ? bZhi[rr] : bZlo[rr]);
      const float o_raw = (pp ? accO1[rr] : accO0[rr]) + (pp ? bOhi[rr] : bOlo[rr]);
      const float cV = pp ? cvHi[rr] : cvLo[rr];
      const float nV = pp ? nvHi[rr] : nvLo[rr];
      const float mV = pp ? mvHi[rr] : mvLo[rr];
      float ef  = __expf(-f_raw);
      float den = 1.0f + ef;
      float fg  = __builtin_amdgcn_rcpf(den);   // sigmoid(f_raw)
      float lgf = -__logf(den);                 // log sigmoid(f_raw)
      float mnv = fmaxf(lgf + mV, i_raw);       // m_new
      float ip  = __expf(i_raw - mnv);          // i'
      float zt  = tanhf_fast(z_raw);
      float og  = __builtin_amdgcn_rcpf(1.0f + __expf(-o_raw));
      float cnv = fg * cV + ip * zt;            // c_new (f' == f per source)
      float nnv = fg * nV + ip;                 // n_new
      float hnv = og * tanhf_fast(cnv * __builtin_amdgcn_rcpf(nnv));
      if (pp == 0) { hnLo[rr] = hnv; cnLo[rr] = cnv; nnLo[rr] = nnv; mnLo[rr] = mnv; }
      else         { hnHi[rr] = hnv; cnHi[rr] = cnv; nnHi[rr] = nnv; mnHi[rr] = mnv; }
    }
    const size_t pbase = rbase + cb;
    *reinterpret_cast<f32x4*>(out + pbase)                = hnLo;
    *reinterpret_cast<f32x4*>(out + pbase + 4)            = hnHi;
    *reinterpret_cast<f32x4*>(out + OUTQ + pbase)         = cnLo;
    *reinterpret_cast<f32x4*>(out + OUTQ + pbase + 4)     = cnHi;
    *reinterpret_cast<f32x4*>(out + 2 * OUTQ + pbase)     = nnLo;
    *reinterpret_cast<f32x4*>(out + 2 * OUTQ + pbase + 4) = nnHi;
    *reinterpret_cast<f32x4*>(out + 3 * OUTQ + pbase)     = mnLo;
    *reinterpret_cast<f32x4*>(out + 3 * OUTQ + pbase + 4) = mnHi;
  }
}

extern "C" void kernel_launch(void* const* d_in, const int* in_sizes, int n_in,
                              void* d_out, int out_size, void* d_ws, size_t ws_size,
                              hipStream_t stream) {
  const float* x = (const float*)d_in[0];
  const float* h = (const float*)d_in[1];
  const float* c = (const float*)d_in[2];
  const float* n = (const float*)d_in[3];
  const float* m = (const float*)d_in[4];
  const float* W = (const float*)d_in[5];
  const float* r = (const float*)d_in[6];
  const float* b = (const float*)d_in[7];
  uint16_t* Bp = (uint16_t*)d_ws;   // 256 KB packed bf16 weights

  pack_weights<<<64, 256, 0, stream>>>(W, r, Bp);
  slstm_fused<<<NROWS / 64, 256, 0, stream>>>(x, h, c, n, m, b, Bp, (float*)d_out);
}

// Round 14
// 150.085 us; speedup vs baseline: 2.0588x; 2.0588x over previous
//
#include <hip/hip_runtime.h>
#include <cstdint>

#define NROWS 131072
#define HD    128      // H == IN == 128
#define NDIM  512      // 4*H
#define OUTQ  16777216 // NROWS*HD

using bf16x8 = __attribute__((ext_vector_type(8))) short;
using f32x4  = __attribute__((ext_vector_type(4))) float;

__device__ __forceinline__ uint32_t bf16rne(float f) {
  uint32_t u = __builtin_bit_cast(uint32_t, f);
  return (u + 0x7fffu + ((u >> 16) & 1u)) >> 16;
}

__device__ __forceinline__ float tanhf_fast(float v) {
  float a = __builtin_fabsf(v);
  float e = __expf(-2.0f * a);
  float t = (1.0f - e) * __builtin_amdgcn_rcpf(1.0f + e);
  return v < 0.0f ? -t : t;
}

__device__ __forceinline__ f32x4 ldv(const float* p) {
  return *reinterpret_cast<const f32x4*>(p);
}

// Async global->LDS DMA, 16B per lane. LDS dest = uniform base + lane*16.
#define ASYNC16(g, l)                                                        \
  __builtin_amdgcn_global_load_lds(                                          \
      (const __attribute__((address_space(1))) void*)(g),                    \
      (__attribute__((address_space(3))) void*)(l), 16, 0, 0)

// Pack Wf[k][n] = W[k][n] + (k>=128 ? r[k-128][n] : 0) as bf16 A-fragments
// of Wf^T with a PERMUTED row->gate-col map (identical to R11).
// Half-step u = t2*2+p: A-row m -> within-gate col t2*32+(m>>2)*8+p*4+(m&3),
// so a lane's D fragments over p=0,1 cover 8 CONTIGUOUS cols t2*32+lg*8..+7.
__global__ __launch_bounds__(256) void pack_weights(
    const float* __restrict__ W, const float* __restrict__ r,
    uint16_t* __restrict__ Bp) {
  int idx = blockIdx.x * 256 + threadIdx.x;   // 16384 frags total
  int l  = idx & 63;
  int ts = idx >> 6;
  int s  = ts & 7;
  int t  = ts >> 3;          // 0..31 = g*8 + u
  int g  = t >> 3;
  int u  = t & 7;
  int t2 = u >> 1;
  int p  = u & 1;
  int m  = l & 15;           // A-row index held by this lane
  int ncol  = g * 128 + t2 * 32 + ((m >> 2) << 3) + p * 4 + (m & 3);
  int kbase = s * 32 + ((l >> 4) << 3);
  uint32_t w[4];
#pragma unroll
  for (int jj = 0; jj < 4; ++jj) {
    int k0 = kbase + 2 * jj;
    float v0 = W[k0 * NDIM + ncol];
    float v1 = W[(k0 + 1) * NDIM + ncol];
    if (k0 >= 128)     v0 += r[(k0 - 128) * NDIM + ncol];
    if (k0 + 1 >= 128) v1 += r[(k0 + 1 - 128) * NDIM + ncol];
    w[jj] = bf16rne(v0) | (bf16rne(v1) << 16);
  }
  reinterpret_cast<uint4*>(Bp)[idx] = make_uint4(w[0], w[1], w[2], w[3]);
}

// 256 threads = 4 waves x 16 rows = 64 rows/block; 2048 blocks.
// Double-buffered 2x32KB weight LDS: DMA(u+1) issued right after the barrier
// that publishes buf(u); drained one full MFMA(+epilogue) phase later.
__global__ __launch_bounds__(256, 2) void slstm_fused(
    const float* __restrict__ x,  const float* __restrict__ h,
    const float* __restrict__ cs, const float* __restrict__ ns,
    const float* __restrict__ ms, const float* __restrict__ bias,
    const uint16_t* __restrict__ Bp, float* __restrict__ out) {
  __shared__ __align__(16) char smem[65536];
  const int tid  = threadIdx.x;
  const int wave = tid >> 6;
  const int lane = tid & 63;
  const int row0 = blockIdx.x * 64;
  const int l15  = lane & 15;
  const int lg   = lane >> 4;

  const int    myrow = row0 + wave * 16 + l15;
  const size_t rbase = (size_t)myrow * HD;
  const int    jb8   = lg * 8;   // lane's contiguous 8-col base in mega-tile

  const char* wBytes = (const char*)Bp;
  // wave w stages gate w's 8 frags (8 KB) per half-step.
#define DMA_HALFSTEP(u)                                                      \
  {                                                                          \
    const char* gsrc = wBytes + (((size_t)(wave * 8 + (u)) * 8) << 10) + (lane << 4); \
    char* ldst = smem + (((u) & 1) << 15) + (wave << 13);                    \
    _Pragma("unroll")                                                        \
    for (int k = 0; k < 8; ++k)                                              \
      ASYNC16(gsrc + (k << 10), ldst + (k << 10));                           \
  }

  // c/n/m mega-tile-0 prefetch (issued first: longest cover)
  f32x4 cvA = ldv(cs + rbase + jb8), cvHiA = ldv(cs + rbase + jb8 + 4);
  f32x4 nvA = ldv(ns + rbase + jb8), nvHiA = ldv(ns + rbase + jb8 + 4);
  f32x4 mvA = ldv(ms + rbase + jb8), mvHiA = ldv(ms + rbase + jb8 + 4);

  DMA_HALFSTEP(0)   // into buf0

  // B-operand fragments direct from global: xh[myrow][s*32+lg*8+j], 32B contig.
  bf16x8 a[8];
#pragma unroll
  for (int s = 0; s < 8; ++s) {
    const float* src = (s < 4 ? x : h) + rbase + ((s & 3) * 32 + lg * 8);
    f32x4 v0 = ldv(src);
    f32x4 v1 = ldv(src + 4);
    bf16x8 pk;
    pk[0] = (short)bf16rne(v0[0]);
    pk[1] = (short)bf16rne(v0[1]);
    pk[2] = (short)bf16rne(v0[2]);
    pk[3] = (short)bf16rne(v0[3]);
    pk[4] = (short)bf16rne(v1[0]);
    pk[5] = (short)bf16rne(v1[1]);
    pk[6] = (short)bf16rne(v1[2]);
    pk[7] = (short)bf16rne(v1[3]);
    a[s] = pk;
  }

#define MFMA_PHASE(u, AI, AF, AZ, AO)                                        \
  {                                                                          \
    const char* wb = smem + (((u) & 1) << 15);                               \
    _Pragma("unroll")                                                        \
    for (int s = 0; s < 8; ++s) {                                            \
      const int lo = lane << 4;                                              \
      bf16x8 wI = *reinterpret_cast<const bf16x8*>(wb + ((0 * 8 + s) << 10) + lo); \
      bf16x8 wF = *reinterpret_cast<const bf16x8*>(wb + ((1 * 8 + s) << 10) + lo); \
      bf16x8 wZ = *reinterpret_cast<const bf16x8*>(wb + ((2 * 8 + s) << 10) + lo); \
      bf16x8 wO = *reinterpret_cast<const bf16x8*>(wb + ((3 * 8 + s) << 10) + lo); \
      AI = __builtin_amdgcn_mfma_f32_16x16x32_bf16(wI, a[s], AI, 0, 0, 0);   \
      AF = __builtin_amdgcn_mfma_f32_16x16x32_bf16(wF, a[s], AF, 0, 0, 0);   \
      AZ = __builtin_amdgcn_mfma_f32_16x16x32_bf16(wZ, a[s], AZ, 0, 0, 0);   \
      AO = __builtin_amdgcn_mfma_f32_16x16x32_bf16(wO, a[s], AO, 0, 0, 0);   \
    }                                                                        \
  }

  // ---- 4 mega-tiles x 2 half-steps, fully unrolled ----
#pragma unroll
  for (int t2 = 0; t2 < 4; ++t2) {
    const int u0 = 2 * t2, u1 = u0 + 1;
    const int cb = t2 * 32 + jb8;

    const f32x4 cvLo = cvA,   cvHi = cvHiA;
    const f32x4 nvLo = nvA,   nvHi = nvHiA;
    const f32x4 mvLo = mvA,   mvHi = mvHiA;

    __syncthreads();   // DMA(u0) landed in buf(u0&1); prior reads/stores done
    DMA_HALFSTEP(u1)   // into the other buffer; drained at next barrier

    f32x4 accI0 = {0,0,0,0}, accF0 = {0,0,0,0}, accZ0 = {0,0,0,0}, accO0 = {0,0,0,0};
    MFMA_PHASE(u0, accI0, accF0, accZ0, accO0)

    __syncthreads();   // DMA(u1) landed (covered by MFMA p0); p0 reads done
    if (t2 < 3) DMA_HALFSTEP(u0 + 2)   // next mega-tile's p0 into buf(even)

    // biases (L2-hot)
    const f32x4 bIlo = ldv(bias + cb),        bIhi = ldv(bias + cb + 4);
    const f32x4 bFlo = ldv(bias + 128 + cb),  bFhi = ldv(bias + 128 + cb + 4);
    const f32x4 bZlo = ldv(bias + 256 + cb),  bZhi = ldv(bias + 256 + cb + 4);
    const f32x4 bOlo = ldv(bias + 384 + cb),  bOhi = ldv(bias + 384 + cb + 4);

    f32x4 accI1 = {0,0,0,0}, accF1 = {0,0,0,0}, accZ1 = {0,0,0,0}, accO1 = {0,0,0,0};
    MFMA_PHASE(u1, accI1, accF1, accZ1, accO1)

    // c/n/m prefetch for t2+1 (drained at next mega-tile's first barrier,
    // covered by the epilogue + stores below)
    if (t2 < 3) {
      const size_t pp = rbase + (t2 + 1) * 32 + jb8;
      cvA = ldv(cs + pp); cvHiA = ldv(cs + pp + 4);
      nvA = ldv(ns + pp); nvHiA = ldv(ns + pp + 4);
      mvA = ldv(ms + pp); mvHiA = ldv(ms + pp + 4);
    }

    // ---- epilogue: 8 contiguous cols/lane -> 2 f32x4 IOs per array ----
    f32x4 hnLo, hnHi, cnLo, cnHi, nnLo, nnHi, mnLo, mnHi;
#pragma unroll
    for (int d = 0; d < 8; ++d) {
      const int pp = d >> 2, rr = d & 3;
      const float i_raw = (pp ? accI1[rr] : accI0[rr]) + (pp ? bIhi[rr] : bIlo[rr]);
      const float f_raw = (pp ? accF1[rr] : accF0[rr]) + (pp ? bFhi[rr] : bFlo[rr]);
      const float z_raw = (pp ? accZ1[rr] : accZ0[rr]) + (pp ? bZhi[rr] : bZlo[rr]);
      const float o_raw = (pp ? accO1[rr] : accO0[rr]) + (pp ? bOhi[rr] : bOlo[rr]);
      const float cV = pp ? cvHi[rr] : cvLo[rr];
      const float nV = pp ? nvHi[rr] : nvLo[rr];
      const float mV = pp ? mvHi[rr] : mvLo[rr];
      float ef  = __expf(-f_raw);
      float den = 1.0f + ef;
      float fg  = __builtin_amdgcn_rcpf(den);   // sigmoid(f_raw)
      float lgf = -__logf(den);                 // log sigmoid(f_raw)
      float mnv = fmaxf(lgf + mV, i_raw);       // m_new
      float ip  = __expf(i_raw - mnv);          // i'
      float zt  = tanhf_fast(z_raw);
      float og  = __builtin_amdgcn_rcpf(1.0f + __expf(-o_raw));
      float cnv = fg * cV + ip * zt;            // c_new (f' == f per source)
      float nnv = fg * nV + ip;                 // n_new
      float hnv = og * tanhf_fast(cnv * __builtin_amdgcn_rcpf(nnv));
      if (pp == 0) { hnLo[rr] = hnv; cnLo[rr] = cnv; nnLo[rr] = nnv; mnLo[rr] = mnv; }
      else         { hnHi[rr] = hnv; cnHi[rr] = cnv; nnHi[rr] = nnv; mnHi[rr] = mnv; }
    }
    const size_t pbase = rbase + cb;
    *reinterpret_cast<f32x4*>(out + pbase)                = hnLo;
    *reinterpret_cast<f32x4*>(out + pbase + 4)            = hnHi;
    *reinterpret_cast<f32x4*>(out + OUTQ + pbase)         = cnLo;
    *reinterpret_cast<f32x4*>(out + OUTQ + pbase + 4)     = cnHi;
    *reinterpret_cast<f32x4*>(out + 2 * OUTQ + pbase)     = nnLo;
    *reinterpret_cast<f32x4*>(out + 2 * OUTQ + pbase + 4) = nnHi;
    *reinterpret_cast<f32x4*>(out + 3 * OUTQ + pbase)     = mnLo;
    *reinterpret_cast<f32x4*>(out + 3 * OUTQ + pbase + 4) = mnHi;
  }
#undef DMA_HALFSTEP
#undef MFMA_PHASE
}

extern "C" void kernel_launch(void* const* d_in, const int* in_sizes, int n_in,
                              void* d_out, int out_size, void* d_ws, size_t ws_size,
                              hipStream_t stream) {
  const float* x = (const float*)d_in[0];
  const float* h = (const float*)d_in[1];
  const float* c = (const float*)d_in[2];
  const float* n = (const float*)d_in[3];
  const float* m = (const float*)d_in[4];
  const float* W = (const float*)d_in[5];
  const float* r = (const float*)d_in[6];
  const float* b = (const float*)d_in[7];
  uint16_t* Bp = (uint16_t*)d_ws;   // 256 KB packed bf16 weights

  pack_weights<<<64, 256, 0, stream>>>(W, r, Bp);
  slstm_fused<<<NROWS / 64, 256, 0, stream>>>(x, h, c, n, m, b, Bp, (float*)d_out);
}

// Round 15
// 149.320 us; speedup vs baseline: 2.0693x; 1.0051x over previous
//
#include <hip/hip_runtime.h>
#include <cstdint>

#define NROWS 131072
#define HD    128      // H == IN == 128
#define NDIM  512      // 4*H
#define OUTQ  16777216 // NROWS*HD

using bf16x8 = __attribute__((ext_vector_type(8))) short;
using f32x4  = __attribute__((ext_vector_type(4))) float;

__device__ __forceinline__ uint32_t bf16rne(float f) {
  uint32_t u = __builtin_bit_cast(uint32_t, f);
  return (u + 0x7fffu + ((u >> 16) & 1u)) >> 16;
}

__device__ __forceinline__ float tanhf_fast(float v) {
  float a = __builtin_fabsf(v);
  float e = __expf(-2.0f * a);
  float t = (1.0f - e) * __builtin_amdgcn_rcpf(1.0f + e);
  return v < 0.0f ? -t : t;
}

__device__ __forceinline__ f32x4 ldv(const float* p) {
  return *reinterpret_cast<const f32x4*>(p);
}

// Async global->LDS DMA, 16B per lane. LDS dest = uniform base + lane*16.
#define ASYNC16(g, l)                                                        \
  __builtin_amdgcn_global_load_lds(                                          \
      (const __attribute__((address_space(1))) void*)(g),                    \
      (__attribute__((address_space(3))) void*)(l), 16, 0, 0)

// Pack Wf[k][n] = W[k][n] + (k>=128 ? r[k-128][n] : 0) as bf16 A-fragments
// of Wf^T with a PERMUTED row->gate-col map (identical to R11).
// Half-step u = t2*2+p: A-row m -> within-gate col t2*32+(m>>2)*8+p*4+(m&3),
// so a lane's D fragments over p=0,1 cover 8 CONTIGUOUS cols t2*32+lg*8..+7.
__global__ __launch_bounds__(256) void pack_weights(
    const float* __restrict__ W, const float* __restrict__ r,
    uint16_t* __restrict__ Bp) {
  int idx = blockIdx.x * 256 + threadIdx.x;   // 16384 frags total
  int l  = idx & 63;
  int ts = idx >> 6;
  int s  = ts & 7;
  int t  = ts >> 3;          // 0..31 = g*8 + u
  int g  = t >> 3;
  int u  = t & 7;
  int t2 = u >> 1;
  int p  = u & 1;
  int m  = l & 15;           // A-row index held by this lane
  int ncol  = g * 128 + t2 * 32 + ((m >> 2) << 3) + p * 4 + (m & 3);
  int kbase = s * 32 + ((l >> 4) << 3);
  uint32_t w[4];
#pragma unroll
  for (int jj = 0; jj < 4; ++jj) {
    int k0 = kbase + 2 * jj;
    float v0 = W[k0 * NDIM + ncol];
    float v1 = W[(k0 + 1) * NDIM + ncol];
    if (k0 >= 128)     v0 += r[(k0 - 128) * NDIM + ncol];
    if (k0 + 1 >= 128) v1 += r[(k0 + 1 - 128) * NDIM + ncol];
    w[jj] = bf16rne(v0) | (bf16rne(v1) << 16);
  }
  reinterpret_cast<uint4*>(Bp)[idx] = make_uint4(w[0], w[1], w[2], w[3]);
}

// 256 threads = 4 waves x 16 rows = 64 rows/block; 2048 blocks.
// LDS: [0,32K) weight half-step buffer; [32K,64K) store-transpose buffer
// sbuf[4 arrays][64 rows][128 B], XOR-swizzled (quad ^= row&7).
// Stores leave the wave as 8-row x 128B-full-line instructions.
__global__ __launch_bounds__(256, 2) void slstm_fused(
    const float* __restrict__ x,  const float* __restrict__ h,
    const float* __restrict__ cs, const float* __restrict__ ns,
    const float* __restrict__ ms, const float* __restrict__ bias,
    const uint16_t* __restrict__ Bp, float* __restrict__ out) {
  __shared__ __align__(16) char smem[65536];
  const int tid  = threadIdx.x;
  const int wave = tid >> 6;
  const int lane = tid & 63;
  const int row0 = blockIdx.x * 64;
  const int l15  = lane & 15;
  const int lg   = lane >> 4;

  const int    myrow = row0 + wave * 16 + l15;
  const size_t rbase = (size_t)myrow * HD;
  const int    jb8   = lg * 8;      // lane's contiguous 8-col base in mega-tile
  const int    rl    = wave * 16 + l15;   // block-local row 0..63

  const char* wBytes = (const char*)Bp;
#define DMA_HALFSTEP(u)                                                      \
  {                                                                          \
    const char* gsrc = wBytes + (((size_t)(wave * 8 + (u)) * 8) << 10) + (lane << 4); \
    char* ldst = smem + (wave << 13);                                        \
    _Pragma("unroll")                                                        \
    for (int k = 0; k < 8; ++k)                                              \
      ASYNC16(gsrc + (k << 10), ldst + (k << 10));                           \
  }

  // c/n/m mega-tile-0 prefetch (longest cover)
  f32x4 cvA = ldv(cs + rbase + jb8), cvHiA = ldv(cs + rbase + jb8 + 4);
  f32x4 nvA = ldv(ns + rbase + jb8), nvHiA = ldv(ns + rbase + jb8 + 4);
  f32x4 mvA = ldv(ms + rbase + jb8), mvHiA = ldv(ms + rbase + jb8 + 4);

  DMA_HALFSTEP(0)

  // B-operand fragments direct from global (L1 merges the 16B granules).
  bf16x8 a[8];
#pragma unroll
  for (int s = 0; s < 8; ++s) {
    const float* src = (s < 4 ? x : h) + rbase + ((s & 3) * 32 + lg * 8);
    f32x4 v0 = ldv(src);
    f32x4 v1 = ldv(src + 4);
    bf16x8 pk;
    pk[0] = (short)bf16rne(v0[0]);
    pk[1] = (short)bf16rne(v0[1]);
    pk[2] = (short)bf16rne(v0[2]);
    pk[3] = (short)bf16rne(v0[3]);
    pk[4] = (short)bf16rne(v1[0]);
    pk[5] = (short)bf16rne(v1[1]);
    pk[6] = (short)bf16rne(v1[2]);
    pk[7] = (short)bf16rne(v1[3]);
    a[s] = pk;
  }

#define MFMA_PHASE(AI, AF, AZ, AO)                                           \
  {                                                                          \
    _Pragma("unroll")                                                        \
    for (int s = 0; s < 8; ++s) {                                            \
      const int lo = lane << 4;                                              \
      bf16x8 wI = *reinterpret_cast<const bf16x8*>(smem + ((0 * 8 + s) << 10) + lo); \
      bf16x8 wF = *reinterpret_cast<const bf16x8*>(smem + ((1 * 8 + s) << 10) + lo); \
      bf16x8 wZ = *reinterpret_cast<const bf16x8*>(smem + ((2 * 8 + s) << 10) + lo); \
      bf16x8 wO = *reinterpret_cast<const bf16x8*>(smem + ((3 * 8 + s) << 10) + lo); \
      AI = __builtin_amdgcn_mfma_f32_16x16x32_bf16(wI, a[s], AI, 0, 0, 0);   \
      AF = __builtin_amdgcn_mfma_f32_16x16x32_bf16(wF, a[s], AF, 0, 0, 0);   \
      AZ = __builtin_amdgcn_mfma_f32_16x16x32_bf16(wZ, a[s], AZ, 0, 0, 0);   \
      AO = __builtin_amdgcn_mfma_f32_16x16x32_bf16(wO, a[s], AO, 0, 0, 0);   \
    }                                                                        \
  }

  char* sbuf = smem + 32768;

  // ---- 4 mega-tiles, fully unrolled ----
#pragma unroll
  for (int t2 = 0; t2 < 4; ++t2) {
    const int cb = t2 * 32 + jb8;

    const f32x4 cvLo = cvA,   cvHi = cvHiA;
    const f32x4 nvLo = nvA,   nvHi = nvHiA;
    const f32x4 mvLo = mvA,   mvHi = mvHiA;

    __syncthreads();   // A: p0 weights visible; sbuf free (prev readout done)

    f32x4 accI0 = {0,0,0,0}, accF0 = {0,0,0,0}, accZ0 = {0,0,0,0}, accO0 = {0,0,0,0};
    MFMA_PHASE(accI0, accF0, accZ0, accO0)

    __syncthreads();   // B: p0 reads done
    DMA_HALFSTEP(2 * t2 + 1)
    __syncthreads();   // C: p1 visible (drain covered by MFMA p0)

    // biases (L2-hot) + c/n/m prefetch for t2+1 (drains at X, ~700cy cover)
    const f32x4 bIlo = ldv(bias + cb),        bIhi = ldv(bias + cb + 4);
    const f32x4 bFlo = ldv(bias + 128 + cb),  bFhi = ldv(bias + 128 + cb + 4);
    const f32x4 bZlo = ldv(bias + 256 + cb),  bZhi = ldv(bias + 256 + cb + 4);
    const f32x4 bOlo = ldv(bias + 384 + cb),  bOhi = ldv(bias + 384 + cb + 4);
    if (t2 < 3) {
      const size_t pp = rbase + (t2 + 1) * 32 + jb8;
      cvA = ldv(cs + pp); cvHiA = ldv(cs + pp + 4);
      nvA = ldv(ns + pp); nvHiA = ldv(ns + pp + 4);
      mvA = ldv(ms + pp); mvHiA = ldv(ms + pp + 4);
    }

    f32x4 accI1 = {0,0,0,0}, accF1 = {0,0,0,0}, accZ1 = {0,0,0,0}, accO1 = {0,0,0,0};
    MFMA_PHASE(accI1, accF1, accZ1, accO1)

    // ---- epilogue compute ----
    f32x4 hnLo, hnHi, cnLo, cnHi, nnLo, nnHi, mnLo, mnHi;
#pragma unroll
    for (int d = 0; d < 8; ++d) {
      const int pp = d >> 2, rr = d & 3;
      const float i_raw = (pp ? accI1[rr] : accI0[rr]) + (pp ? bIhi[rr] : bIlo[rr]);
      const float f_raw = (pp ? accF1[rr] : accF0[rr]) + (pp ? bFhi[rr] : bFlo[rr]);
      const float z_raw = (pp ? accZ1[rr] : accZ0[rr]) + (pp ? bZhi[rr] : bZlo[rr]);
      const float o_raw = (pp ? accO1[rr] : accO0[rr]) + (pp ? bOhi[rr] : bOlo[rr]);
      const float cV = pp ? cvHi[rr] : cvLo[rr];
      const float nV = pp ? nvHi[rr] : nvLo[rr];
      const float mV = pp ? mvHi[rr] : mvLo[rr];
      float ef  = __expf(-f_raw);
      float den = 1.0f + ef;
      float fg  = __builtin_amdgcn_rcpf(den);   // sigmoid(f_raw)
      float lgf = -__logf(den);                 // log sigmoid(f_raw)
      float mnv = fmaxf(lgf + mV, i_raw);       // m_new
      float ip  = __expf(i_raw - mnv);          // i'
      float zt  = tanhf_fast(z_raw);
      float og  = __builtin_amdgcn_rcpf(1.0f + __expf(-o_raw));
      float cnv = fg * cV + ip * zt;            // c_new (f' == f per source)
      float nnv = fg * nV + ip;                 // n_new
      float hnv = og * tanhf_fast(cnv * __builtin_amdgcn_rcpf(nnv));
      if (pp == 0) { hnLo[rr] = hnv; cnLo[rr] = cnv; nnLo[rr] = nnv; mnLo[rr] = mnv; }
      else         { hnHi[rr] = hnv; cnHi[rr] = cnv; nnHi[rr] = nnv; mnHi[rr] = mnv; }
    }

    // ---- stage outputs into sbuf (swizzled: quad ^= rl&7) ----
    // chunk index k (16B) of row rl stored at byte rl*128 + ((k ^ (rl&7))<<4)
    {
      const int rb   = rl << 7;
      const int sw   = rl & 7;
      const int kLo  = (lg << 1);
      const int kHi  = (lg << 1) | 1;
      const int oLo  = rb + (((kLo) ^ sw) << 4);
      const int oHi  = rb + (((kHi) ^ sw) << 4);
      *reinterpret_cast<f32x4*>(sbuf + 0 * 8192 + oLo) = hnLo;
      *reinterpret_cast<f32x4*>(sbuf + 0 * 8192 + oHi) = hnHi;
      *reinterpret_cast<f32x4*>(sbuf + 1 * 8192 + oLo) = cnLo;
      *reinterpret_cast<f32x4*>(sbuf + 1 * 8192 + oHi) = cnHi;
      *reinterpret_cast<f32x4*>(sbuf + 2 * 8192 + oLo) = nnLo;
      *reinterpret_cast<f32x4*>(sbuf + 2 * 8192 + oHi) = nnHi;
      *reinterpret_cast<f32x4*>(sbuf + 3 * 8192 + oLo) = mnLo;
      *reinterpret_cast<f32x4*>(sbuf + 3 * 8192 + oHi) = mnHi;
    }
    __syncthreads();   // X: sbuf visible; p1 weight reads done

    if (t2 < 3) DMA_HALFSTEP(2 * t2 + 2)   // next p0; drains at next A

    // ---- readout: wave w stores array w, 8 rows x 128B per instruction ----
    {
      float* abase = out + (size_t)wave * OUTQ + (size_t)row0 * HD + t2 * 32;
      const char* sb = sbuf + (wave << 13);
#pragma unroll
      for (int i = 0; i < 8; ++i) {
        const int r  = i * 8 + (lane >> 3);
        const int k  = lane & 7;
        f32x4 v = *reinterpret_cast<const f32x4*>(
            sb + (r << 7) + (((k ^ (r & 7))) << 4));
        *reinterpret_cast<f32x4*>(abase + (size_t)r * HD + k * 4) = v;
      }
    }
  }
#undef DMA_HALFSTEP
#undef MFMA_PHASE
}

extern "C" void kernel_launch(void* const* d_in, const int* in_sizes, int n_in,
                              void* d_out, int out_size, void* d_ws, size_t ws_size,
                              hipStream_t stream) {
  const float* x = (const float*)d_in[0];
  const float* h = (const float*)d_in[1];
  const float* c = (const float*)d_in[2];
  const float* n = (const float*)d_in[3];
  const float* m = (const float*)d_in[4];
  const float* W = (const float*)d_in[5];
  const float* r = (const float*)d_in[6];
  const float* b = (const float*)d_in[7];
  uint16_t* Bp = (uint16_t*)d_ws;   // 256 KB packed bf16 weights

  pack_weights<<<64, 256, 0, stream>>>(W, r, Bp);
  slstm_fused<<<NROWS / 64, 256, 0, stream>>>(x, h, c, n, m, b, Bp, (float*)d_out);
}

// Round 16
// 141.748 us; speedup vs baseline: 2.1799x; 1.0534x over previous
//
#include <hip/hip_runtime.h>
#include <cstdint>

#define NROWS 131072
#define HD    128      // H == IN == 128
#define NDIM  512      // 4*H
#define OUTQ  16777216 // NROWS*HD

using bf16x8 = __attribute__((ext_vector_type(8))) short;
using f32x4  = __attribute__((ext_vector_type(4))) float;

__device__ __forceinline__ uint32_t bf16rne(float f) {
  uint32_t u = __builtin_bit_cast(uint32_t, f);
  return (u + 0x7fffu + ((u >> 16) & 1u)) >> 16;
}

__device__ __forceinline__ float tanhf_fast(float v) {
  float a = __builtin_fabsf(v);
  float e = __expf(-2.0f * a);
  float t = (1.0f - e) * __builtin_amdgcn_rcpf(1.0f + e);
  return v < 0.0f ? -t : t;
}

__device__ __forceinline__ f32x4 ldv(const float* p) {
  return *reinterpret_cast<const f32x4*>(p);
}

// Async global->LDS DMA, 16B per lane. LDS dest = uniform base + lane*16.
#define ASYNC16(g, l)                                                        \
  __builtin_amdgcn_global_load_lds(                                          \
      (const __attribute__((address_space(1))) void*)(g),                    \
      (__attribute__((address_space(3))) void*)(l), 16, 0, 0)

// Pack Wf[k][n] = W[k][n] + (k>=128 ? r[k-128][n] : 0) as bf16 A-fragments
// of Wf^T with a PERMUTED row->gate-col map (identical to R11).
// Half-step u = t2*2+p: A-row m -> within-gate col t2*32+(m>>2)*8+p*4+(m&3),
// so a lane's D fragments over p=0,1 cover 8 CONTIGUOUS cols t2*32+lg*8..+7.
__global__ __launch_bounds__(256) void pack_weights(
    const float* __restrict__ W, const float* __restrict__ r,
    uint16_t* __restrict__ Bp) {
  int idx = blockIdx.x * 256 + threadIdx.x;   // 16384 frags total
  int l  = idx & 63;
  int ts = idx >> 6;
  int s  = ts & 7;
  int t  = ts >> 3;          // 0..31 = g*8 + u
  int g  = t >> 3;
  int u  = t & 7;
  int t2 = u >> 1;
  int p  = u & 1;
  int m  = l & 15;           // A-row index held by this lane
  int ncol  = g * 128 + t2 * 32 + ((m >> 2) << 3) + p * 4 + (m & 3);
  int kbase = s * 32 + ((l >> 4) << 3);
  uint32_t w[4];
#pragma unroll
  for (int jj = 0; jj < 4; ++jj) {
    int k0 = kbase + 2 * jj;
    float v0 = W[k0 * NDIM + ncol];
    float v1 = W[(k0 + 1) * NDIM + ncol];
    if (k0 >= 128)     v0 += r[(k0 - 128) * NDIM + ncol];
    if (k0 + 1 >= 128) v1 += r[(k0 + 1 - 128) * NDIM + ncol];
    w[jj] = bf16rne(v0) | (bf16rne(v1) << 16);
  }
  reinterpret_cast<uint4*>(Bp)[idx] = make_uint4(w[0], w[1], w[2], w[3]);
}

// 256 threads = 4 waves x 16 rows = 64 rows/block; 2048 blocks.
// LDS: [0,32K) weight half-step buffer; [32K,64K) store-transpose buffer
// sbuf[4 arrays][64 rows][128 B], XOR-swizzled (quad ^= row&7).
// Readout: full-128B-line NONTEMPORAL stores (bypass L3 so the 256MB
// write stream stops evicting the 320MB input stream from Infinity Cache).
__global__ __launch_bounds__(256, 2) void slstm_fused(
    const float* __restrict__ x,  const float* __restrict__ h,
    const float* __restrict__ cs, const float* __restrict__ ns,
    const float* __restrict__ ms, const float* __restrict__ bias,
    const uint16_t* __restrict__ Bp, float* __restrict__ out) {
  __shared__ __align__(16) char smem[65536];
  const int tid  = threadIdx.x;
  const int wave = tid >> 6;
  const int lane = tid & 63;
  const int row0 = blockIdx.x * 64;
  const int l15  = lane & 15;
  const int lg   = lane >> 4;

  const int    myrow = row0 + wave * 16 + l15;
  const size_t rbase = (size_t)myrow * HD;
  const int    jb8   = lg * 8;      // lane's contiguous 8-col base in mega-tile
  const int    rl    = wave * 16 + l15;   // block-local row 0..63

  const char* wBytes = (const char*)Bp;
#define DMA_HALFSTEP(u)                                                      \
  {                                                                          \
    const char* gsrc = wBytes + (((size_t)(wave * 8 + (u)) * 8) << 10) + (lane << 4); \
    char* ldst = smem + (wave << 13);                                        \
    _Pragma("unroll")                                                        \
    for (int k = 0; k < 8; ++k)                                              \
      ASYNC16(gsrc + (k << 10), ldst + (k << 10));                           \
  }

  // c/n/m mega-tile-0 prefetch (longest cover)
  f32x4 cvA = ldv(cs + rbase + jb8), cvHiA = ldv(cs + rbase + jb8 + 4);
  f32x4 nvA = ldv(ns + rbase + jb8), nvHiA = ldv(ns + rbase + jb8 + 4);
  f32x4 mvA = ldv(ms + rbase + jb8), mvHiA = ldv(ms + rbase + jb8 + 4);

  DMA_HALFSTEP(0)

  // B-operand fragments direct from global (L1 merges the 16B granules).
  bf16x8 a[8];
#pragma unroll
  for (int s = 0; s < 8; ++s) {
    const float* src = (s < 4 ? x : h) + rbase + ((s & 3) * 32 + lg * 8);
    f32x4 v0 = ldv(src);
    f32x4 v1 = ldv(src + 4);
    bf16x8 pk;
    pk[0] = (short)bf16rne(v0[0]);
    pk[1] = (short)bf16rne(v0[1]);
    pk[2] = (short)bf16rne(v0[2]);
    pk[3] = (short)bf16rne(v0[3]);
    pk[4] = (short)bf16rne(v1[0]);
    pk[5] = (short)bf16rne(v1[1]);
    pk[6] = (short)bf16rne(v1[2]);
    pk[7] = (short)bf16rne(v1[3]);
    a[s] = pk;
  }

#define MFMA_PHASE(AI, AF, AZ, AO)                                           \
  {                                                                          \
    _Pragma("unroll")                                                        \
    for (int s = 0; s < 8; ++s) {                                            \
      const int lo = lane << 4;                                              \
      bf16x8 wI = *reinterpret_cast<const bf16x8*>(smem + ((0 * 8 + s) << 10) + lo); \
      bf16x8 wF = *reinterpret_cast<const bf16x8*>(smem + ((1 * 8 + s) << 10) + lo); \
      bf16x8 wZ = *reinterpret_cast<const bf16x8*>(smem + ((2 * 8 + s) << 10) + lo); \
      bf16x8 wO = *reinterpret_cast<const bf16x8*>(smem + ((3 * 8 + s) << 10) + lo); \
      AI = __builtin_amdgcn_mfma_f32_16x16x32_bf16(wI, a[s], AI, 0, 0, 0);   \
      AF = __builtin_amdgcn_mfma_f32_16x16x32_bf16(wF, a[s], AF, 0, 0, 0);   \
      AZ = __builtin_amdgcn_mfma_f32_16x16x32_bf16(wZ, a[s], AZ, 0, 0, 0);   \
      AO = __builtin_amdgcn_mfma_f32_16x16x32_bf16(wO, a[s], AO, 0, 0, 0);   \
    }                                                                        \
  }

  char* sbuf = smem + 32768;

  // ---- 4 mega-tiles, fully unrolled ----
#pragma unroll
  for (int t2 = 0; t2 < 4; ++t2) {
    const int cb = t2 * 32 + jb8;

    const f32x4 cvLo = cvA,   cvHi = cvHiA;
    const f32x4 nvLo = nvA,   nvHi = nvHiA;
    const f32x4 mvLo = mvA,   mvHi = mvHiA;

    __syncthreads();   // A: p0 weights visible; sbuf free (prev readout done)

    f32x4 accI0 = {0,0,0,0}, accF0 = {0,0,0,0}, accZ0 = {0,0,0,0}, accO0 = {0,0,0,0};
    MFMA_PHASE(accI0, accF0, accZ0, accO0)

    __syncthreads();   // B: p0 reads done
    DMA_HALFSTEP(2 * t2 + 1)
    __syncthreads();   // C: p1 visible (drain covered by MFMA p0)

    // biases (L2-hot) + c/n/m prefetch for t2+1 (drains at X, ~700cy cover)
    const f32x4 bIlo = ldv(bias + cb),        bIhi = ldv(bias + cb + 4);
    const f32x4 bFlo = ldv(bias + 128 + cb),  bFhi = ldv(bias + 128 + cb + 4);
    const f32x4 bZlo = ldv(bias + 256 + cb),  bZhi = ldv(bias + 256 + cb + 4);
    const f32x4 bOlo = ldv(bias + 384 + cb),  bOhi = ldv(bias + 384 + cb + 4);
    if (t2 < 3) {
      const size_t pp = rbase + (t2 + 1) * 32 + jb8;
      cvA = ldv(cs + pp); cvHiA = ldv(cs + pp + 4);
      nvA = ldv(ns + pp); nvHiA = ldv(ns + pp + 4);
      mvA = ldv(ms + pp); mvHiA = ldv(ms + pp + 4);
    }

    f32x4 accI1 = {0,0,0,0}, accF1 = {0,0,0,0}, accZ1 = {0,0,0,0}, accO1 = {0,0,0,0};
    MFMA_PHASE(accI1, accF1, accZ1, accO1)

    // ---- epilogue compute ----
    f32x4 hnLo, hnHi, cnLo, cnHi, nnLo, nnHi, mnLo, mnHi;
#pragma unroll
    for (int d = 0; d < 8; ++d) {
      const int pp = d >> 2, rr = d & 3;
      const float i_raw = (pp ? accI1[rr] : accI0[rr]) + (pp ? bIhi[rr] : bIlo[rr]);
      const float f_raw = (pp ? accF1[rr] : accF0[rr]) + (pp ? bFhi[rr] : bFlo[rr]);
      const float z_raw = (pp ? accZ1[rr] : accZ0[rr]) + (pp ? bZhi[rr] : bZlo[rr]);
      const float o_raw = (pp ? accO1[rr] : accO0[rr]) + (pp ? bOhi[rr] : bOlo[rr]);
      const float cV = pp ? cvHi[rr] : cvLo[rr];
      const float nV = pp ? nvHi[rr] : nvLo[rr];
      const float mV = pp ? mvHi[rr] : mvLo[rr];
      float ef  = __expf(-f_raw);
      float den = 1.0f + ef;
      float fg  = __builtin_amdgcn_rcpf(den);   // sigmoid(f_raw)
      float lgf = -__logf(den);                 // log sigmoid(f_raw)
      float mnv = fmaxf(lgf + mV, i_raw);       // m_new
      float ip  = __expf(i_raw - mnv);          // i'
      float zt  = tanhf_fast(z_raw);
      float og  = __builtin_amdgcn_rcpf(1.0f + __expf(-o_raw));
      float cnv = fg * cV + ip * zt;            // c_new (f' == f per source)
      float nnv = fg * nV + ip;                 // n_new
      float hnv = og * tanhf_fast(cnv * __builtin_amdgcn_rcpf(nnv));
      if (pp == 0) { hnLo[rr] = hnv; cnLo[rr] = cnv; nnLo[rr] = nnv; mnLo[rr] = mnv; }
      else         { hnHi[rr] = hnv; cnHi[rr] = cnv; nnHi[rr] = nnv; mnHi[rr] = mnv; }
    }

    // ---- stage outputs into sbuf (swizzled: quad ^= rl&7) ----
    {
      const int rb   = rl << 7;
      const int sw   = rl & 7;
      const int kLo  = (lg << 1);
      const int kHi  = (lg << 1) | 1;
      const int oLo  = rb + (((kLo) ^ sw) << 4);
      const int oHi  = rb + (((kHi) ^ sw) << 4);
      *reinterpret_cast<f32x4*>(sbuf + 0 * 8192 + oLo) = hnLo;
      *reinterpret_cast<f32x4*>(sbuf + 0 * 8192 + oHi) = hnHi;
      *reinterpret_cast<f32x4*>(sbuf + 1 * 8192 + oLo) = cnLo;
      *reinterpret_cast<f32x4*>(sbuf + 1 * 8192 + oHi) = cnHi;
      *reinterpret_cast<f32x4*>(sbuf + 2 * 8192 + oLo) = nnLo;
      *reinterpret_cast<f32x4*>(sbuf + 2 * 8192 + oHi) = nnHi;
      *reinterpret_cast<f32x4*>(sbuf + 3 * 8192 + oLo) = mnLo;
      *reinterpret_cast<f32x4*>(sbuf + 3 * 8192 + oHi) = mnHi;
    }
    __syncthreads();   // X: sbuf visible; p1 weight reads done

    if (t2 < 3) DMA_HALFSTEP(2 * t2 + 2)   // next p0; drains at next A

    // ---- readout: wave w stores array w, 8 rows x 128B per instruction,
    //      NONTEMPORAL (full lines -> clean HBM writes, no L3 allocation) ----
    {
      float* abase = out + (size_t)wave * OUTQ + (size_t)row0 * HD + t2 * 32;
      const char* sb = sbuf + (wave << 13);
#pragma unroll
      for (int i = 0; i < 8; ++i) {
        const int r  = i * 8 + (lane >> 3);
        const int k  = lane & 7;
        f32x4 v = *reinterpret_cast<const f32x4*>(
            sb + (r << 7) + (((k ^ (r & 7))) << 4));
        __builtin_nontemporal_store(
            v, reinterpret_cast<f32x4*>(abase + (size_t)r * HD + k * 4));
      }
    }
  }
#undef DMA_HALFSTEP
#undef MFMA_PHASE
}

extern "C" void kernel_launch(void* const* d_in, const int* in_sizes, int n_in,
                              void* d_out, int out_size, void* d_ws, size_t ws_size,
                              hipStream_t stream) {
  const float* x = (const float*)d_in[0];
  const float* h = (const float*)d_in[1];
  const float* c = (const float*)d_in[2];
  const float* n = (const float*)d_in[3];
  const float* m = (const float*)d_in[4];
  const float* W = (const float*)d_in[5];
  const float* r = (const float*)d_in[6];
  const float* b = (const float*)d_in[7];
  uint16_t* Bp = (uint16_t*)d_ws;   // 256 KB packed bf16 weights

  pack_weights<<<64, 256, 0, stream>>>(W, r, Bp);
  slstm_fused<<<NROWS / 64, 256, 0, stream>>>(x, h, c, n, m, b, Bp, (float*)d_out);
}

// Round 17
// 131.080 us; speedup vs baseline: 2.3573x; 1.0814x over previous
//
#include <hip/hip_runtime.h>
#include <cstdint>

#define NROWS 131072
#define HD    128      // H == IN == 128
#define NDIM  512      // 4*H
#define OUTQ  16777216 // NROWS*HD

using bf16x8 = __attribute__((ext_vector_type(8))) short;
using f32x4  = __attribute__((ext_vector_type(4))) float;

#define SB() __builtin_amdgcn_sched_barrier(0)

__device__ __forceinline__ uint32_t bf16rne(float f) {
  uint32_t u = __builtin_bit_cast(uint32_t, f);
  return (u + 0x7fffu + ((u >> 16) & 1u)) >> 16;
}

__device__ __forceinline__ float tanhf_fast(float v) {
  float a = __builtin_fabsf(v);
  float e = __expf(-2.0f * a);
  float t = (1.0f - e) * __builtin_amdgcn_rcpf(1.0f + e);
  return v < 0.0f ? -t : t;
}

__device__ __forceinline__ f32x4 ldv(const float* p) {
  return *reinterpret_cast<const f32x4*>(p);
}

// Async global->LDS DMA, 16B per lane. LDS dest = uniform base + lane*16.
#define ASYNC16(g, l)                                                        \
  __builtin_amdgcn_global_load_lds(                                          \
      (const __attribute__((address_space(1))) void*)(g),                    \
      (__attribute__((address_space(3))) void*)(l), 16, 0, 0)

// Pack Wf[k][n] = W[k][n] + (k>=128 ? r[k-128][n] : 0) as bf16 A-fragments
// of Wf^T with a PERMUTED row->gate-col map (identical to R11).
// Half-step u = t2*2+p: A-row m -> within-gate col t2*32+(m>>2)*8+p*4+(m&3),
// so a lane's D fragments over p=0,1 cover 8 CONTIGUOUS cols t2*32+lg*8..+7.
__global__ __launch_bounds__(256) void pack_weights(
    const float* __restrict__ W, const float* __restrict__ r,
    uint16_t* __restrict__ Bp) {
  int idx = blockIdx.x * 256 + threadIdx.x;   // 16384 frags total
  int l  = idx & 63;
  int ts = idx >> 6;
  int s  = ts & 7;
  int t  = ts >> 3;          // 0..31 = g*8 + u
  int g  = t >> 3;
  int u  = t & 7;
  int t2 = u >> 1;
  int p  = u & 1;
  int m  = l & 15;           // A-row index held by this lane
  int ncol  = g * 128 + t2 * 32 + ((m >> 2) << 3) + p * 4 + (m & 3);
  int kbase = s * 32 + ((l >> 4) << 3);
  uint32_t w[4];
#pragma unroll
  for (int jj = 0; jj < 4; ++jj) {
    int k0 = kbase + 2 * jj;
    float v0 = W[k0 * NDIM + ncol];
    float v1 = W[(k0 + 1) * NDIM + ncol];
    if (k0 >= 128)     v0 += r[(k0 - 128) * NDIM + ncol];
    if (k0 + 1 >= 128) v1 += r[(k0 + 1 - 128) * NDIM + ncol];
    w[jj] = bf16rne(v0) | (bf16rne(v1) << 16);
  }
  reinterpret_cast<uint4*>(Bp)[idx] = make_uint4(w[0], w[1], w[2], w[3]);
}

// 256 threads = 4 waves x 16 rows = 64 rows/block; 2048 blocks.
// LDS: [0,32K) weight half-step buffer; [32K,64K) store-transpose sbuf.
// Raw barriers with COUNTED vmcnt: NT stores are never drained at barrier A
// (vmcnt(8) retires the DMA, stores stay in flight ~1.5 phases).
__global__ __launch_bounds__(256, 2) void slstm_fused(
    const float* __restrict__ x,  const float* __restrict__ h,
    const float* __restrict__ cs, const float* __restrict__ ns,
    const float* __restrict__ ms, const float* __restrict__ bias,
    const uint16_t* __restrict__ Bp, float* __restrict__ out) {
  __shared__ __align__(16) char smem[65536];
  const int tid  = threadIdx.x;
  const int wave = tid >> 6;
  const int lane = tid & 63;
  const int row0 = blockIdx.x * 64;
  const int l15  = lane & 15;
  const int lg   = lane >> 4;

  const int    myrow = row0 + wave * 16 + l15;
  const size_t rbase = (size_t)myrow * HD;
  const int    jb8   = lg * 8;      // lane's contiguous 8-col base in mega-tile
  const int    rl    = wave * 16 + l15;   // block-local row 0..63

  const char* wBytes = (const char*)Bp;
#define DMA_HALFSTEP(u)                                                      \
  {                                                                          \
    const char* gsrc = wBytes + (((size_t)(wave * 8 + (u)) * 8) << 10) + (lane << 4); \
    char* ldst = smem + (wave << 13);                                        \
    _Pragma("unroll")                                                        \
    for (int k = 0; k < 8; ++k)                                              \
      ASYNC16(gsrc + (k << 10), ldst + (k << 10));                           \
  }

  // c/n/m mega-tile-0 prefetch (longest cover)
  f32x4 cvA = ldv(cs + rbase + jb8), cvHiA = ldv(cs + rbase + jb8 + 4);
  f32x4 nvA = ldv(ns + rbase + jb8), nvHiA = ldv(ns + rbase + jb8 + 4);
  f32x4 mvA = ldv(ms + rbase + jb8), mvHiA = ldv(ms + rbase + jb8 + 4);

  DMA_HALFSTEP(0)

  // B-operand fragments direct from global (L1 merges the 16B granules).
  bf16x8 a[8];
#pragma unroll
  for (int s = 0; s < 8; ++s) {
    const float* src = (s < 4 ? x : h) + rbase + ((s & 3) * 32 + lg * 8);
    f32x4 v0 = ldv(src);
    f32x4 v1 = ldv(src + 4);
    bf16x8 pk;
    pk[0] = (short)bf16rne(v0[0]);
    pk[1] = (short)bf16rne(v0[1]);
    pk[2] = (short)bf16rne(v0[2]);
    pk[3] = (short)bf16rne(v0[3]);
    pk[4] = (short)bf16rne(v1[0]);
    pk[5] = (short)bf16rne(v1[1]);
    pk[6] = (short)bf16rne(v1[2]);
    pk[7] = (short)bf16rne(v1[3]);
    a[s] = pk;
  }
  __syncthreads();   // prologue: full drain once (DMA0 + a-loads + cnm0)

#define MFMA_PHASE(AI, AF, AZ, AO)                                           \
  {                                                                          \
    _Pragma("unroll")                                                        \
    for (int s = 0; s < 8; ++s) {                                            \
      const int lo = lane << 4;                                              \
      bf16x8 wI = *reinterpret_cast<const bf16x8*>(smem + ((0 * 8 + s) << 10) + lo); \
      bf16x8 wF = *reinterpret_cast<const bf16x8*>(smem + ((1 * 8 + s) << 10) + lo); \
      bf16x8 wZ = *reinterpret_cast<const bf16x8*>(smem + ((2 * 8 + s) << 10) + lo); \
      bf16x8 wO = *reinterpret_cast<const bf16x8*>(smem + ((3 * 8 + s) << 10) + lo); \
      AI = __builtin_amdgcn_mfma_f32_16x16x32_bf16(wI, a[s], AI, 0, 0, 0);   \
      AF = __builtin_amdgcn_mfma_f32_16x16x32_bf16(wF, a[s], AF, 0, 0, 0);   \
      AZ = __builtin_amdgcn_mfma_f32_16x16x32_bf16(wZ, a[s], AZ, 0, 0, 0);   \
      AO = __builtin_amdgcn_mfma_f32_16x16x32_bf16(wO, a[s], AO, 0, 0, 0);   \
    }                                                                        \
  }

  char* sbuf = smem + 32768;

  // ---- 4 mega-tiles, fully unrolled ----
#pragma unroll
  for (int t2 = 0; t2 < 4; ++t2) {
    const int cb = t2 * 32 + jb8;

    const f32x4 cvLo = cvA,   cvHi = cvHiA;
    const f32x4 nvLo = nvA,   nvHi = nvHiA;
    const f32x4 mvLo = mvA,   mvHi = mvHiA;

    // A: DMA-p0 (issued at prev X, BEFORE the stores) landed. vmcnt(8)
    // retires it while the <=8 NT stores stay in flight.
    SB(); asm volatile("s_waitcnt vmcnt(8)" ::: "memory"); SB();
    __builtin_amdgcn_s_barrier(); SB();

    f32x4 accI0 = {0,0,0,0}, accF0 = {0,0,0,0}, accZ0 = {0,0,0,0}, accO0 = {0,0,0,0};
    MFMA_PHASE(accI0, accF0, accZ0, accO0)

    // B: all waves done reading p0 weights (program order); no vm wait.
    SB(); __builtin_amdgcn_s_barrier(); SB();
    DMA_HALFSTEP(2 * t2 + 1)
    SB();
    // C: DMA-p1 landed (in-order => also drains the ~1.5-phase-old stores).
    asm volatile("s_waitcnt vmcnt(0)" ::: "memory"); SB();
    __builtin_amdgcn_s_barrier(); SB();

    // biases (L2-hot) + c/n/m prefetch for t2+1
    const f32x4 bIlo = ldv(bias + cb),        bIhi = ldv(bias + cb + 4);
    const f32x4 bFlo = ldv(bias + 128 + cb),  bFhi = ldv(bias + 128 + cb + 4);
    const f32x4 bZlo = ldv(bias + 256 + cb),  bZhi = ldv(bias + 256 + cb + 4);
    const f32x4 bOlo = ldv(bias + 384 + cb),  bOhi = ldv(bias + 384 + cb + 4);
    if (t2 < 3) {
      const size_t pp = rbase + (t2 + 1) * 32 + jb8;
      cvA = ldv(cs + pp); cvHiA = ldv(cs + pp + 4);
      nvA = ldv(ns + pp); nvHiA = ldv(ns + pp + 4);
      mvA = ldv(ms + pp); mvHiA = ldv(ms + pp + 4);
    }

    f32x4 accI1 = {0,0,0,0}, accF1 = {0,0,0,0}, accZ1 = {0,0,0,0}, accO1 = {0,0,0,0};
    MFMA_PHASE(accI1, accF1, accZ1, accO1)

    // ---- epilogue compute ----
    f32x4 hnLo, hnHi, cnLo, cnHi, nnLo, nnHi, mnLo, mnHi;
#pragma unroll
    for (int d = 0; d < 8; ++d) {
      const int pp = d >> 2, rr = d & 3;
      const float i_raw = (pp ? accI1[rr] : accI0[rr]) + (pp ? bIhi[rr] : bIlo[rr]);
      const float f_raw = (pp ? accF1[rr] : accF0[rr]) + (pp ? bFhi[rr] : bFlo[rr]);
      const float z_raw = (pp ? accZ1[rr] : accZ0[rr]) + (pp ? bZhi[rr] : bZlo[rr]);
      const float o_raw = (pp ? accO1[rr] : accO0[rr]) + (pp ? bOhi[rr] : bOlo[rr]);
      const float cV = pp ? cvHi[rr] : cvLo[rr];
      const float nV = pp ? nvHi[rr] : nvLo[rr];
      const float mV = pp ? mvHi[rr] : mvLo[rr];
      float ef  = __expf(-f_raw);
      float den = 1.0f + ef;
      float fg  = __builtin_amdgcn_rcpf(den);   // sigmoid(f_raw)
      float lgf = -__logf(den);                 // log sigmoid(f_raw)
      float mnv = fmaxf(lgf + mV, i_raw);       // m_new
      float ip  = __expf(i_raw - mnv);          // i'
      float zt  = tanhf_fast(z_raw);
      float og  = __builtin_amdgcn_rcpf(1.0f + __expf(-o_raw));
      float cnv = fg * cV + ip * zt;            // c_new (f' == f per source)
      float nnv = fg * nV + ip;                 // n_new
      float hnv = og * tanhf_fast(cnv * __builtin_amdgcn_rcpf(nnv));
      if (pp == 0) { hnLo[rr] = hnv; cnLo[rr] = cnv; nnLo[rr] = nnv; mnLo[rr] = mnv; }
      else         { hnHi[rr] = hnv; cnHi[rr] = cnv; nnHi[rr] = nnv; mnHi[rr] = mnv; }
    }

    // ---- stage outputs into sbuf (swizzled: quad ^= rl&7) ----
    {
      const int rb   = rl << 7;
      const int sw   = rl & 7;
      const int kLo  = (lg << 1);
      const int kHi  = (lg << 1) | 1;
      const int oLo  = rb + (((kLo) ^ sw) << 4);
      const int oHi  = rb + (((kHi) ^ sw) << 4);
      *reinterpret_cast<f32x4*>(sbuf + 0 * 8192 + oLo) = hnLo;
      *reinterpret_cast<f32x4*>(sbuf + 0 * 8192 + oHi) = hnHi;
      *reinterpret_cast<f32x4*>(sbuf + 1 * 8192 + oLo) = cnLo;
      *reinterpret_cast<f32x4*>(sbuf + 1 * 8192 + oHi) = cnHi;
      *reinterpret_cast<f32x4*>(sbuf + 2 * 8192 + oLo) = nnLo;
      *reinterpret_cast<f32x4*>(sbuf + 2 * 8192 + oHi) = nnHi;
      *reinterpret_cast<f32x4*>(sbuf + 3 * 8192 + oLo) = mnLo;
      *reinterpret_cast<f32x4*>(sbuf + 3 * 8192 + oHi) = mnHi;
    }
    // X: sbuf writes visible (lgkmcnt only; no vm drain).
    SB(); asm volatile("s_waitcnt lgkmcnt(0)" ::: "memory"); SB();
    __builtin_amdgcn_s_barrier(); SB();

    if (t2 < 3) DMA_HALFSTEP(2 * t2 + 2)   // next p0; retired at next A
    SB();

    // ---- readout: wave w stores array w, 8 rows x 128B per instruction,
    //      NONTEMPORAL full lines; issued AFTER the DMA (vmcnt(8) at A) ----
    {
      float* abase = out + (size_t)wave * OUTQ + (size_t)row0 * HD + t2 * 32;
      const char* sb = sbuf + (wave << 13);
#pragma unroll
      for (int i = 0; i < 8; ++i) {
        const int r  = i * 8 + (lane >> 3);
        const int k  = lane & 7;
        f32x4 v = *reinterpret_cast<const f32x4*>(
            sb + (r << 7) + (((k ^ (r & 7))) << 4));
        __builtin_nontemporal_store(
            v, reinterpret_cast<f32x4*>(abase + (size_t)r * HD + k * 4));
      }
    }
  }
#undef DMA_HALFSTEP
#undef MFMA_PHASE
}

extern "C" void kernel_launch(void* const* d_in, const int* in_sizes, int n_in,
                              void* d_out, int out_size, void* d_ws, size_t ws_size,
                              hipStream_t stream) {
  const float* x = (const float*)d_in[0];
  const float* h = (const float*)d_in[1];
  const float* c = (const float*)d_in[2];
  const float* n = (const float*)d_in[3];
  const float* m = (const float*)d_in[4];
  const float* W = (const float*)d_in[5];
  const float* r = (const float*)d_in[6];
  const float* b = (const float*)d_in[7];
  uint16_t* Bp = (uint16_t*)d_ws;   // 256 KB packed bf16 weights

  pack_weights<<<64, 256, 0, stream>>>(W, r, Bp);
  slstm_fused<<<NROWS / 64, 256, 0, stream>>>(x, h, c, n, m, b, Bp, (float*)d_out);
}

// Round 18
// 130.029 us; speedup vs baseline: 2.3763x; 1.0081x over previous
//
#include <hip/hip_runtime.h>
#include <cstdint>

#define NROWS 131072
#define HD    128      // H == IN == 128
#define NDIM  512      // 4*H
#define OUTQ  16777216 // NROWS*HD

using bf16x8 = __attribute__((ext_vector_type(8))) short;
using f32x4  = __attribute__((ext_vector_type(4))) float;

#define SB() __builtin_amdgcn_sched_barrier(0)

__device__ __forceinline__ uint32_t bf16rne(float f) {
  uint32_t u = __builtin_bit_cast(uint32_t, f);
  return (u + 0x7fffu + ((u >> 16) & 1u)) >> 16;
}

__device__ __forceinline__ float tanhf_fast(float v) {
  float a = __builtin_fabsf(v);
  float e = __expf(-2.0f * a);
  float t = (1.0f - e) * __builtin_amdgcn_rcpf(1.0f + e);
  return v < 0.0f ? -t : t;
}

__device__ __forceinline__ f32x4 ldv(const float* p) {
  return *reinterpret_cast<const f32x4*>(p);
}

// Async global->LDS DMA, 16B per lane. LDS dest = uniform base + lane*16.
#define ASYNC16(g, l)                                                        \
  __builtin_amdgcn_global_load_lds(                                          \
      (const __attribute__((address_space(1))) void*)(g),                    \
      (__attribute__((address_space(3))) void*)(l), 16, 0, 0)

// Pack Wf[k][n] = W[k][n] + (k>=128 ? r[k-128][n] : 0) as bf16 A-fragments
// of Wf^T with a PERMUTED row->gate-col map (identical to R11).
// Half-step u = t2*2+p: A-row m -> within-gate col t2*32+(m>>2)*8+p*4+(m&3),
// so a lane's D fragments over p=0,1 cover 8 CONTIGUOUS cols t2*32+lg*8..+7.
__global__ __launch_bounds__(256) void pack_weights(
    const float* __restrict__ W, const float* __restrict__ r,
    uint16_t* __restrict__ Bp) {
  int idx = blockIdx.x * 256 + threadIdx.x;   // 16384 frags total
  int l  = idx & 63;
  int ts = idx >> 6;
  int s  = ts & 7;
  int t  = ts >> 3;          // 0..31 = g*8 + u
  int g  = t >> 3;
  int u  = t & 7;
  int t2 = u >> 1;
  int p  = u & 1;
  int m  = l & 15;           // A-row index held by this lane
  int ncol  = g * 128 + t2 * 32 + ((m >> 2) << 3) + p * 4 + (m & 3);
  int kbase = s * 32 + ((l >> 4) << 3);
  uint32_t w[4];
#pragma unroll
  for (int jj = 0; jj < 4; ++jj) {
    int k0 = kbase + 2 * jj;
    float v0 = W[k0 * NDIM + ncol];
    float v1 = W[(k0 + 1) * NDIM + ncol];
    if (k0 >= 128)     v0 += r[(k0 - 128) * NDIM + ncol];
    if (k0 + 1 >= 128) v1 += r[(k0 + 1 - 128) * NDIM + ncol];
    w[jj] = bf16rne(v0) | (bf16rne(v1) << 16);
  }
  reinterpret_cast<uint4*>(Bp)[idx] = make_uint4(w[0], w[1], w[2], w[3]);
}

// 256 threads = 4 waves x 16 rows = 64 rows/block; 2048 blocks.
// LDS 80KB: bufA [0,32K) = p0 weights, bufB [32K,64K) = p1 weights,
// sbuf [64K,80K) = 2-array store-transpose buffer.
// BOTH next-tile DMAs issue at X1, BEFORE the tile's stores -> in-order
// vmcnt retires them without ever draining store-acks:
//   A: vmcnt(16) retires {stores(t-2), P0(t)};  C: vmcnt(8) retires P1(t).
__global__ __launch_bounds__(256, 2) void slstm_fused(
    const float* __restrict__ x,  const float* __restrict__ h,
    const float* __restrict__ cs, const float* __restrict__ ns,
    const float* __restrict__ ms, const float* __restrict__ bias,
    const uint16_t* __restrict__ Bp, float* __restrict__ out) {
  __shared__ __align__(16) char smem[81920];
  const int tid  = threadIdx.x;
  const int wave = tid >> 6;
  const int lane = tid & 63;
  const int row0 = blockIdx.x * 64;
  const int l15  = lane & 15;
  const int lg   = lane >> 4;

  const int    myrow = row0 + wave * 16 + l15;
  const size_t rbase = (size_t)myrow * HD;
  const int    jb8   = lg * 8;      // lane's contiguous 8-col base in mega-tile
  const int    rl    = wave * 16 + l15;   // block-local row 0..63

  const char* wBytes = (const char*)Bp;
  // wave w stages gate w's 8 frags (8 KB) per half-step.
#define DMA_HALF(u, base)                                                    \
  {                                                                          \
    const char* gsrc = wBytes + (((size_t)(wave * 8 + (u)) * 8) << 10) + (lane << 4); \
    char* ldst = smem + (base) + (wave << 13);                               \
    _Pragma("unroll")                                                        \
    for (int k = 0; k < 8; ++k)                                              \
      ASYNC16(gsrc + (k << 10), ldst + (k << 10));                           \
  }

  // c/n/m mega-tile-0 prefetch (longest cover)
  f32x4 cvA = ldv(cs + rbase + jb8), cvHiA = ldv(cs + rbase + jb8 + 4);
  f32x4 nvA = ldv(ns + rbase + jb8), nvHiA = ldv(ns + rbase + jb8 + 4);
  f32x4 mvA = ldv(ms + rbase + jb8), mvHiA = ldv(ms + rbase + jb8 + 4);

  DMA_HALF(0, 0)        // P0(0) -> bufA
  DMA_HALF(1, 32768)    // P1(0) -> bufB

  // B-operand fragments direct from global (L1 merges the 16B granules).
  bf16x8 a[8];
#pragma unroll
  for (int s = 0; s < 8; ++s) {
    const float* src = (s < 4 ? x : h) + rbase + ((s & 3) * 32 + lg * 8);
    f32x4 v0 = ldv(src);
    f32x4 v1 = ldv(src + 4);
    bf16x8 pk;
    pk[0] = (short)bf16rne(v0[0]);
    pk[1] = (short)bf16rne(v0[1]);
    pk[2] = (short)bf16rne(v0[2]);
    pk[3] = (short)bf16rne(v0[3]);
    pk[4] = (short)bf16rne(v1[0]);
    pk[5] = (short)bf16rne(v1[1]);
    pk[6] = (short)bf16rne(v1[2]);
    pk[7] = (short)bf16rne(v1[3]);
    a[s] = pk;
  }
  __syncthreads();   // prologue: one full drain (P0/P1(0) + a + cnm landed)

#define MFMA_PHASE(base, AI, AF, AZ, AO)                                     \
  {                                                                          \
    _Pragma("unroll")                                                        \
    for (int s = 0; s < 8; ++s) {                                            \
      const int lo = lane << 4;                                              \
      bf16x8 wI = *reinterpret_cast<const bf16x8*>(smem + (base) + ((0 * 8 + s) << 10) + lo); \
      bf16x8 wF = *reinterpret_cast<const bf16x8*>(smem + (base) + ((1 * 8 + s) << 10) + lo); \
      bf16x8 wZ = *reinterpret_cast<const bf16x8*>(smem + (base) + ((2 * 8 + s) << 10) + lo); \
      bf16x8 wO = *reinterpret_cast<const bf16x8*>(smem + (base) + ((3 * 8 + s) << 10) + lo); \
      AI = __builtin_amdgcn_mfma_f32_16x16x32_bf16(wI, a[s], AI, 0, 0, 0);   \
      AF = __builtin_amdgcn_mfma_f32_16x16x32_bf16(wF, a[s], AF, 0, 0, 0);   \
      AZ = __builtin_amdgcn_mfma_f32_16x16x32_bf16(wZ, a[s], AZ, 0, 0, 0);   \
      AO = __builtin_amdgcn_mfma_f32_16x16x32_bf16(wO, a[s], AO, 0, 0, 0);   \
    }                                                                        \
  }

  char* sbuf = smem + 65536;   // [64K,80K): two 8KB array slots

  // ---- 4 mega-tiles, fully unrolled ----
#pragma unroll
  for (int t2 = 0; t2 < 4; ++t2) {
    const int cb = t2 * 32 + jb8;

    const f32x4 cvLo = cvA,   cvHi = cvHiA;
    const f32x4 nvLo = nvA,   nvHi = nvHiA;
    const f32x4 mvLo = mvA,   mvHi = mvHiA;

    // A: retire {stores(t2-2), P0(t2)}; stores(t2-1) + P1(t2) stay in flight.
    SB(); asm volatile("s_waitcnt vmcnt(16)" ::: "memory"); SB();
    __builtin_amdgcn_s_barrier(); SB();

    f32x4 accI0 = {0,0,0,0}, accF0 = {0,0,0,0}, accZ0 = {0,0,0,0}, accO0 = {0,0,0,0};
    MFMA_PHASE(0, accI0, accF0, accZ0, accO0)

    // C: retire P1(t2) (older than stores(t2-1) is false -> P1 IS oldest now).
    SB(); asm volatile("s_waitcnt vmcnt(8)" ::: "memory"); SB();
    __builtin_amdgcn_s_barrier(); SB();

    // biases (L2-hot) + c/n/m prefetch for t2+1 (consumed next tile)
    const f32x4 bIlo = ldv(bias + cb),        bIhi = ldv(bias + cb + 4);
    const f32x4 bFlo = ldv(bias + 128 + cb),  bFhi = ldv(bias + 128 + cb + 4);
    const f32x4 bZlo = ldv(bias + 256 + cb),  bZhi = ldv(bias + 256 + cb + 4);
    const f32x4 bOlo = ldv(bias + 384 + cb),  bOhi = ldv(bias + 384 + cb + 4);
    if (t2 < 3) {
      const size_t pp = rbase + (t2 + 1) * 32 + jb8;
      cvA = ldv(cs + pp); cvHiA = ldv(cs + pp + 4);
      nvA = ldv(ns + pp); nvHiA = ldv(ns + pp + 4);
      mvA = ldv(ms + pp); mvHiA = ldv(ms + pp + 4);
    }

    f32x4 accI1 = {0,0,0,0}, accF1 = {0,0,0,0}, accZ1 = {0,0,0,0}, accO1 = {0,0,0,0};
    MFMA_PHASE(32768, accI1, accF1, accZ1, accO1)

    // ---- epilogue compute ----
    f32x4 hnLo, hnHi, cnLo, cnHi, nnLo, nnHi, mnLo, mnHi;
#pragma unroll
    for (int d = 0; d < 8; ++d) {
      const int pp = d >> 2, rr = d & 3;
      const float i_raw = (pp ? accI1[rr] : accI0[rr]) + (pp ? bIhi[rr] : bIlo[rr]);
      const float f_raw = (pp ? accF1[rr] : accF0[rr]) + (pp ? bFhi[rr] : bFlo[rr]);
      const float z_raw = (pp ? accZ1[rr] : accZ0[rr]) + (pp ? bZhi[rr] : bZlo[rr]);
      const float o_raw = (pp ? accO1[rr] : accO0[rr]) + (pp ? bOhi[rr] : bOlo[rr]);
      const float cV = pp ? cvHi[rr] : cvLo[rr];
      const float nV = pp ? nvHi[rr] : nvLo[rr];
      const float mV = pp ? mvHi[rr] : mvLo[rr];
      float ef  = __expf(-f_raw);
      float den = 1.0f + ef;
      float fg  = __builtin_amdgcn_rcpf(den);   // sigmoid(f_raw)
      float lgf = -__logf(den);                 // log sigmoid(f_raw)
      float mnv = fmaxf(lgf + mV, i_raw);       // m_new
      float ip  = __expf(i_raw - mnv);          // i'
      float zt  = tanhf_fast(z_raw);
      float og  = __builtin_amdgcn_rcpf(1.0f + __expf(-o_raw));
      float cnv = fg * cV + ip * zt;            // c_new (f' == f per source)
      float nnv = fg * nV + ip;                 // n_new
      float hnv = og * tanhf_fast(cnv * __builtin_amdgcn_rcpf(nnv));
      if (pp == 0) { hnLo[rr] = hnv; cnLo[rr] = cnv; nnLo[rr] = nnv; mnLo[rr] = mnv; }
      else         { hnHi[rr] = hnv; cnHi[rr] = cnv; nnHi[rr] = nnv; mnHi[rr] = mnv; }
    }

    const int rb   = rl << 7;
    const int sw   = rl & 7;
    const int oLo  = rb + ((((lg << 1)    ) ^ sw) << 4);
    const int oHi  = rb + ((((lg << 1) | 1) ^ sw) << 4);

    // ---- round 1: stage h,c ----
    *reinterpret_cast<f32x4*>(sbuf + 0    + oLo) = hnLo;
    *reinterpret_cast<f32x4*>(sbuf + 0    + oHi) = hnHi;
    *reinterpret_cast<f32x4*>(sbuf + 8192 + oLo) = cnLo;
    *reinterpret_cast<f32x4*>(sbuf + 8192 + oHi) = cnHi;
    // X1: sbuf h,c visible
    SB(); asm volatile("s_waitcnt lgkmcnt(0)" ::: "memory"); SB();
    __builtin_amdgcn_s_barrier(); SB();

    if (t2 < 3) {                 // BOTH next-tile DMAs, before any stores
      DMA_HALF(2 * t2 + 2, 0)
      DMA_HALF(2 * t2 + 3, 32768)
    }
    SB();

    // readout round 1: arrays {h,c}; wave w -> array w>>1, rows (w&1)*32..+31
    {
      const int aw  = wave >> 1;
      const int rrb = (wave & 1) * 32;
      const char* sb = sbuf + aw * 8192;
      float* abase = out + (size_t)aw * OUTQ + (size_t)row0 * HD + t2 * 32;
#pragma unroll
      for (int i = 0; i < 4; ++i) {
        const int r = rrb + i * 8 + (lane >> 3);
        const int k = lane & 7;
        f32x4 v = *reinterpret_cast<const f32x4*>(
            sb + (r << 7) + (((k ^ (r & 7))) << 4));
        __builtin_nontemporal_store(
            v, reinterpret_cast<f32x4*>(abase + (size_t)r * HD + k * 4));
      }
    }
    // Xmid: all round-1 ds_reads complete before overwriting sbuf
    SB(); asm volatile("s_waitcnt lgkmcnt(0)" ::: "memory"); SB();
    __builtin_amdgcn_s_barrier(); SB();

    // ---- round 2: stage n,m ----
    *reinterpret_cast<f32x4*>(sbuf + 0    + oLo) = nnLo;
    *reinterpret_cast<f32x4*>(sbuf + 0    + oHi) = nnHi;
    *reinterpret_cast<f32x4*>(sbuf + 8192 + oLo) = mnLo;
    *reinterpret_cast<f32x4*>(sbuf + 8192 + oHi) = mnHi;
    // X2: sbuf n,m visible
    SB(); asm volatile("s_waitcnt lgkmcnt(0)" ::: "memory"); SB();
    __builtin_amdgcn_s_barrier(); SB();

    // readout round 2: arrays {n,m}
    {
      const int aw  = wave >> 1;
      const int rrb = (wave & 1) * 32;
      const char* sb = sbuf + aw * 8192;
      float* abase = out + (size_t)(2 + aw) * OUTQ + (size_t)row0 * HD + t2 * 32;
#pragma unroll
      for (int i = 0; i < 4; ++i) {
        const int r = rrb + i * 8 + (lane >> 3);
        const int k = lane & 7;
        f32x4 v = *reinterpret_cast<const f32x4*>(
            sb + (r << 7) + (((k ^ (r & 7))) << 4));
        __builtin_nontemporal_store(
            v, reinterpret_cast<f32x4*>(abase + (size_t)r * HD + k * 4));
      }
    }
  }
#undef DMA_HALF
#undef MFMA_PHASE
}

extern "C" void kernel_launch(void* const* d_in, const int* in_sizes, int n_in,
                              void* d_out, int out_size, void* d_ws, size_t ws_size,
                              hipStream_t stream) {
  const float* x = (const float*)d_in[0];
  const float* h = (const float*)d_in[1];
  const float* c = (const float*)d_in[2];
  const float* n = (const float*)d_in[3];
  const float* m = (const float*)d_in[4];
  const float* W = (const float*)d_in[5];
  const float* r = (const float*)d_in[6];
  const float* b = (const float*)d_in[7];
  uint16_t* Bp = (uint16_t*)d_ws;   // 256 KB packed bf16 weights

  pack_weights<<<64, 256, 0, stream>>>(W, r, Bp);
  slstm_fused<<<NROWS / 64, 256, 0, stream>>>(x, h, c, n, m, b, Bp, (float*)d_out);
}